// Round 13
// baseline (55.207 us; speedup 1.0000x reference)
//
#include <hip/hip_runtime.h>
#include <hip/hip_bf16.h>

#define HW 128
#define PW 130   // padded width/height

typedef float f32x4 __attribute__((ext_vector_type(4)));
typedef short bf16x8 __attribute__((ext_vector_type(8)));

__device__ __forceinline__ unsigned short f2bf(float v) {
  __hip_bfloat16 h = __float2bfloat16(v);
  return *reinterpret_cast<unsigned short*>(&h);
}

__device__ __forceinline__ void bf8_to_f32(const int4& r, float* f) {
  const unsigned int* u = reinterpret_cast<const unsigned int*>(&r);
#pragma unroll
  for (int k = 0; k < 4; ++k) {
    f[2 * k]     = __uint_as_float(u[k] << 16);
    f[2 * k + 1] = __uint_as_float(u[k] & 0xffff0000u);
  }
}

__device__ __forceinline__ void gld_lds16(const void* g, void* l) {
  __builtin_amdgcn_global_load_lds(
      (const __attribute__((address_space(1))) void*)g,
      (__attribute__((address_space(3))) void*)l, 16, 0, 0);
}

// ---------------- k_tr: prep + border-zero + NCHW->padded-NHWC transpose ----------------
// wtbs[(t*64+o)*64 + ((c8^(o&7))*8)+cj] = bf16(w[o][c][t])   (r8-verified, LDS-stageable)
// wb: offsets-conv B frags (r8-verified layout).
__global__ __launch_bounds__(256) void k_tr(const float* __restrict__ x,
                                            unsigned int* __restrict__ xt_u32,
                                            const float* __restrict__ w,
                                            const float* __restrict__ w_off,
                                            unsigned short* __restrict__ wtbs,
                                            unsigned short* __restrict__ wb) {
  __shared__ float tile[64 * 129];
  int blk = blockIdx.x;                   // b*128 + h
  int tid = threadIdx.x;
  int gi = blk * 256 + tid;

  // ---- folded prep ----
  if (blk < 144) {
    if (gi < 36864) {
      int o = gi & 63, tc = gi >> 6;
      int c = tc & 63, t = tc >> 6;
      float v = w[o * 576 + c * 9 + t];
      int c8 = c >> 3, cj = c & 7;
      wtbs[(t * 64 + o) * 64 + (((c8 ^ (o & 7)) << 3) + cj)] = f2bf(v);
    }
    if (gi < 18432) {
      int j = gi & 7, lane = (gi >> 3) & 63, f = gi >> 9;
      int n = f & 1, kk = (f >> 1) & 1, t = f >> 2;
      int o = n * 16 + (lane & 15);
      int c = kk * 32 + (lane >> 4) * 8 + j;
      float v = (o < 18) ? w_off[o * 576 + c * 9 + t] : 0.0f;
      wb[gi] = f2bf(v);
    }
  }
  // ---- folded border zero: 2064 cells * 8 int4 ----
  if (gi < 16512) {
    int c4 = gi & 7, ci = gi >> 3;
    int b = ci / 516, cell = ci - b * 516;
    int row, col;
    if (cell < 130)      { row = 0;   col = cell; }
    else if (cell < 260) { row = 129; col = cell - 130; }
    else { int k = cell - 260; row = 1 + (k >> 1); col = (k & 1) ? 129 : 0; }
    reinterpret_cast<int4*>(xt_u32 + ((size_t)(b * PW + row) * PW + col) * 32)[c4] =
        make_int4(0, 0, 0, 0);
  }

  // ---- transpose (r8-verified) ----
  int h = blk & 127, b = blk >> 7;
  int w0 = tid & 127, ch = tid >> 7;
  const float* xb = x + ((size_t)b * 64 * HW + h) * HW;
#pragma unroll
  for (int k = 0; k < 32; ++k) {
    int c = ch * 32 + k;
    tile[c * 129 + (w0 ^ (c & 1))] = xb[c * (HW * HW) + w0];
  }
  __syncthreads();
  int c2 = tid & 31, wg = tid >> 5;
#pragma unroll
  for (int k = 0; k < 16; ++k) {
    int ww = wg * 16 + k;
    float lo = tile[(2 * c2) * 129 + ww];
    float hi = tile[(2 * c2 + 1) * 129 + (ww ^ 1)];
    xt_u32[((size_t)(b * PW + h + 1) * PW + (ww + 1)) * 32 + c2] =
        (unsigned int)f2bf(lo) | ((unsigned int)f2bf(hi) << 16);
  }
}

// ---------------- k_fuse: phase-0 conv + A-in-register gather + MFMA GEMM ----------------
// Wave tiling: wave w owns M=16 pixels (w*16..+15) x N=64 outputs.
// Thread (l15=pixel, l4=chunk) gathers/lerps exactly its A-fragment channels
// (chunks l4 and l4+4) -> A never touches LDS; 1 barrier/tap (B dbuf only).
// LDS 29952 B: phase-0 slab [0,25344) (union: ldsB dbuf [0,16384)); loff @25344.
__global__ __launch_bounds__(256) void k_fuse(const unsigned short* __restrict__ xt,
                                              const unsigned short* __restrict__ wb,
                                              const unsigned short* __restrict__ wtbs,
                                              const float* __restrict__ b_off,
                                              const float* __restrict__ bias,
                                              float* __restrict__ out) {
  __shared__ __align__(16) char u_lds[29952];
  char* slab_b = u_lds;
  unsigned short* slab_us = (unsigned short*)u_lds;
  float* loff = (float*)(u_lds + 25344);

  int bid = blockIdx.x;
  bid = (bid & 7) * 128 + (bid >> 3);     // XCD swizzle (1024 % 8 == 0)
  int pix0 = bid * 64;
  int h = (pix0 >> 7) & 127, b = pix0 >> 14, wbase = pix0 & 127;

  int tid = threadIdx.x;
  int wid = tid >> 6, lane = tid & 63;
  int l15 = lane & 15, l4 = lane >> 4;

  const unsigned short* xb = xt + (size_t)b * (PW * PW * 64);

  // ======== phase 0: offsets conv (r8/r11-verified) ========
  for (int i = wid; i < 25; i += 4) {
    int e = i * 512 + lane * 8;
    if (e < 12672) {
      int S = e >> 6, c8 = (e >> 3) & 7;
      int r = S / 66, u = S - r * 66;
      gld_lds16(xb + ((size_t)((h + r) * PW + wbase + u)) * 64 + ((c8 ^ (S & 7)) << 3),
                &slab_us[i * 512]);
    }
  }

  const int4* wb4 = reinterpret_cast<const int4*>(wb);
  int4 bc[4], bn[4];
#pragma unroll
  for (int q = 0; q < 4; ++q) bc[q] = wb4[q * 64 + lane];
  asm volatile("s_waitcnt vmcnt(0)" ::: "memory");
  __builtin_amdgcn_s_barrier();

  f32x4 acc0 = {0.f, 0.f, 0.f, 0.f}, acc1 = {0.f, 0.f, 0.f, 0.f};
#pragma unroll 1
  for (int t = 0; t < 9; ++t) {
    if (t < 8) {
#pragma unroll
      for (int q = 0; q < 4; ++q) bn[q] = wb4[((t + 1) * 4 + q) * 64 + lane];
    }
    int ti = t / 3, tj = t - ti * 3;
    int S = ti * 66 + (wid * 16 + l15) + tj;
#pragma unroll
    for (int kk = 0; kk < 2; ++kk) {
      int phys = (kk * 4 + l4) ^ (S & 7);
      bf16x8 a = *reinterpret_cast<const bf16x8*>(slab_b + S * 128 + phys * 16);
      acc0 = __builtin_amdgcn_mfma_f32_16x16x32_bf16(a, *(const bf16x8*)&bc[kk * 2 + 0], acc0, 0, 0, 0);
      acc1 = __builtin_amdgcn_mfma_f32_16x16x32_bf16(a, *(const bf16x8*)&bc[kk * 2 + 1], acc1, 0, 0, 0);
    }
#pragma unroll
    for (int q = 0; q < 4; ++q) bc[q] = bn[q];
  }
  {
    float bo0 = b_off[l15];
    int pl = wid * 16 + l4 * 4;
#pragma unroll
    for (int reg = 0; reg < 4; ++reg)
      loff[(pl + reg) * 18 + l15] = acc0[reg] + bo0;
    if (l15 < 2) {
      float bo1 = b_off[16 + l15];
#pragma unroll
      for (int reg = 0; reg < 4; ++reg)
        loff[(pl + reg) * 18 + 16 + l15] = acc1[reg] + bo1;
    }
  }
  __syncthreads();   // slab reads done (ldsB union next) + loff visible

  // ======== main loop ========
  auto ldsBp = [&](int s) { return u_lds + s * 8192; };

  auto stageB = [&](int t, int bsel) {
#pragma unroll
    for (int j = 0; j < 2; ++j) {
      int instr = j * 4 + wid;
      int cg = instr * 64 + lane;
      int row = cg >> 3, c8 = cg & 7;
      gld_lds16(wtbs + ((size_t)(t * 64 + row) * 64 + c8 * 8),
                (unsigned short*)ldsBp(bsel) + instr * 512);
    }
  };

  int p = wid * 16 + l15;                 // this thread's pixel (0..63)
  int pxx = wbase + p;                    // its x coordinate
  const float* lp = loff + p * 18;
  const unsigned short* xch = xb + l4 * 8;  // chunk-l4 base

  int4 rc[8];
  float fw0, fw1, fw2, fw3;

  auto gather = [&](int t) {
    int ti = t / 3, tj = t % 3;
    float2 d = *reinterpret_cast<const float2*>(lp + 2 * t);
    float py = (float)(h + ti - 1) + d.x;
    float px = (float)(pxx + tj - 1) + d.y;
    float y0f = floorf(py), x0f = floorf(px);
    float wy = py - y0f, wxf = px - x0f;
    int y0 = (int)y0f, x0 = (int)x0f;
    int y1 = y0 + 1, x1 = x0 + 1;
    fw0 = (((unsigned)y0 < HW) && ((unsigned)x0 < HW)) ? (1.f - wy) * (1.f - wxf) : 0.f;
    fw1 = (((unsigned)y0 < HW) && ((unsigned)x1 < HW)) ? (1.f - wy) * wxf : 0.f;
    fw2 = (((unsigned)y1 < HW) && ((unsigned)x0 < HW)) ? wy * (1.f - wxf) : 0.f;
    fw3 = (((unsigned)y1 < HW) && ((unsigned)x1 < HW)) ? wy * wxf : 0.f;
    int y0c = min(max(y0, 0), HW - 1) + 1, y1c = min(max(y1, 0), HW - 1) + 1;
    int x0c = min(max(x0, 0), HW - 1) + 1, x1c = min(max(x1, 0), HW - 1) + 1;
    const unsigned short* b00 = xch + ((size_t)y0c * PW + x0c) * 64;
    const unsigned short* b01 = xch + ((size_t)y0c * PW + x1c) * 64;
    const unsigned short* b10 = xch + ((size_t)y1c * PW + x0c) * 64;
    const unsigned short* b11 = xch + ((size_t)y1c * PW + x1c) * 64;
    rc[0] = *reinterpret_cast<const int4*>(b00);       // chunk l4
    rc[1] = *reinterpret_cast<const int4*>(b00 + 32);  // chunk l4+4
    rc[2] = *reinterpret_cast<const int4*>(b01);
    rc[3] = *reinterpret_cast<const int4*>(b01 + 32);
    rc[4] = *reinterpret_cast<const int4*>(b10);
    rc[5] = *reinterpret_cast<const int4*>(b10 + 32);
    rc[6] = *reinterpret_cast<const int4*>(b11);
    rc[7] = *reinterpret_cast<const int4*>(b11 + 32);
  };

  int4 af[2];                             // A-fragments: kk=0 -> chunk l4, kk=1 -> chunk l4+4
  auto lerp = [&]() {
#pragma unroll
    for (int j = 0; j < 2; ++j) {
      float v00[8], v01[8], v10[8], v11[8];
      bf8_to_f32(rc[0 + j], v00); bf8_to_f32(rc[2 + j], v01);
      bf8_to_f32(rc[4 + j], v10); bf8_to_f32(rc[6 + j], v11);
      unsigned int pk[4];
#pragma unroll
      for (int jj = 0; jj < 4; ++jj) {
        float slo = fmaf(v11[2 * jj], fw3,
                    fmaf(v10[2 * jj], fw2,
                    fmaf(v01[2 * jj], fw1, v00[2 * jj] * fw0)));
        float shi = fmaf(v11[2 * jj + 1], fw3,
                    fmaf(v10[2 * jj + 1], fw2,
                    fmaf(v01[2 * jj + 1], fw1, v00[2 * jj + 1] * fw0)));
        pk[jj] = (unsigned int)f2bf(slo) | ((unsigned int)f2bf(shi) << 16);
      }
      af[j] = *reinterpret_cast<int4*>(pk);
    }
  };

  f32x4 acc[4];
#pragma unroll
  for (int fn = 0; fn < 4; ++fn) acc[fn] = {0.f, 0.f, 0.f, 0.f};

  // prologue: B0 staged; A0 gathered+lerped in registers
  stageB(0, 0);
  gather(0);
  lerp();
  asm volatile("s_waitcnt vmcnt(0)" ::: "memory");
  __syncthreads();                        // ldsB0 ready

#pragma unroll 1
  for (int t = 0; t < 9; ++t) {
    int cur = t & 1;
    if (t < 8) {
      stageB(t + 1, cur ^ 1);
      gather(t + 1);                      // private VMEM, in flight under MFMA
    }
    const char* Bb = ldsBp(cur);
#pragma unroll
    for (int kk = 0; kk < 2; ++kk) {
#pragma unroll
      for (int fn = 0; fn < 4; ++fn) {
        int row = fn * 16 + l15;
        bf16x8 bf = *reinterpret_cast<const bf16x8*>(
            Bb + row * 128 + (((kk * 4 + l4) ^ (row & 7)) << 4));
        acc[fn] = __builtin_amdgcn_mfma_f32_16x16x32_bf16(
            *reinterpret_cast<const bf16x8*>(&af[kk]), bf, acc[fn], 0, 0, 0);
      }
    }
    if (t < 8) lerp();                    // af for t+1 (waits rc; drains gld_lds too)
    __syncthreads();                      // all waves done reading ldsB[cur]; ldsB[cur^1] complete
  }

  // epilogue: D col=l15 -> o (within fn-tile), row=l4*4+reg -> pixel
  int hwbase = (pix0 & 16383) + wid * 16 + l4 * 4;
  int bb = pix0 >> 14;
#pragma unroll
  for (int fn = 0; fn < 4; ++fn) {
    int o = fn * 16 + l15;
    float bz = bias[o];
    float4 st = make_float4(acc[fn][0] + bz, acc[fn][1] + bz,
                            acc[fn][2] + bz, acc[fn][3] + bz);
    *reinterpret_cast<float4*>(&out[(((size_t)bb * 64 + o) << 14) + hwbase]) = st;
  }
}

extern "C" void kernel_launch(void* const* d_in, const int* in_sizes, int n_in,
                              void* d_out, int out_size, void* d_ws, size_t ws_size,
                              hipStream_t stream) {
  const float* x     = (const float*)d_in[0];
  const float* w_off = (const float*)d_in[1];
  const float* b_off = (const float*)d_in[2];
  const float* w     = (const float*)d_in[3];
  const float* bias  = (const float*)d_in[4];
  float* out = (float*)d_out;
  char* ws   = (char*)d_ws;

  // ws layout (BYTES):
  //   wtbs [0,       73,728)      36,864 bf16 (main-GEMM B, chunk-swizzled)
  //   wb   [73,728,  110,592)     18,432 bf16 (offsets-conv B frags)
  //   xt   [110,592, 8,763,392)   4*130*130*64 bf16 (padded, zero border)
  unsigned short* wtbs = (unsigned short*)(ws);
  unsigned short* wb   = (unsigned short*)(ws + 73728);
  unsigned short* xt   = (unsigned short*)(ws + 110592);

  hipLaunchKernelGGL(k_tr,   dim3(512),  dim3(256), 0, stream,
                     x, (unsigned int*)xt, w, w_off, wtbs, wb);
  hipLaunchKernelGGL(k_fuse, dim3(1024), dim3(256), 0, stream,
                     xt, wb, wtbs, b_off, bias, out);
}